// Round 15
// baseline (87.517 us; speedup 1.0000x reference)
//
#include <hip/hip_runtime.h>
#include <hip/hip_bf16.h>
#include <math.h>

#define N_NODES 50000
#define N_EDGES 1600000
#define IN_F 256
#define OUT_F 64

#define NB 196            // buckets (bucket = dst >> 8, 256 nodes each)
#define CAP 10752         // per-bucket region stride (words)
#define BK_BLOCKS 391     // bucket-scatter blocks, 4096 edges each
#define EPB 4096
#define GEMM_BLOCKS 782   // 64 rows each

typedef short short8 __attribute__((ext_vector_type(8)));
typedef float f32x4 __attribute__((ext_vector_type(4)));

__device__ __forceinline__ unsigned short f2bf(float f) {
    union { __hip_bfloat16 h; unsigned short u; } v;
    v.h = __float2bfloat16(f);
    return v.u;
}
__device__ __forceinline__ float bf2f(unsigned u) {
    return __uint_as_float(u << 16);
}

// ---------------- K0: prep — W -> fragment-ordered bf16 wfrag; zero cnt ---
__global__ __launch_bounds__(256) void k_prep(const float* __restrict__ W,
                                              unsigned short* __restrict__ wfrag,
                                              int* __restrict__ cnt) {
    const int tid = threadIdx.x;
    if (blockIdx.x == 0 && tid < NB) cnt[tid] = 0;
    int c = blockIdx.x * 256 + tid;
    int ct = c >> 9, kt = (c >> 6) & 7, cl = c & 63;
    int col = ct * 16 + (cl & 15);
    int kb = kt * 32 + 8 * (cl >> 4);
    const float* p = W + col * 256 + kb;
    float4 x = *(const float4*)p;
    float4 y = *(const float4*)(p + 4);
    short8 v;
    v[0] = f2bf(x.x); v[1] = f2bf(x.y); v[2] = f2bf(x.z); v[3] = f2bf(x.w);
    v[4] = f2bf(y.x); v[5] = f2bf(y.y); v[6] = f2bf(y.z); v[7] = f2bf(y.w);
    *(short8*)(wfrag + c * 8) = v;
}

// ---------------- K1: fused [gemm | bucket] ----------------
// Gemm blocks: Wh = feat @ W^T (bf16 MFMA), epilogue quantizes each row to
// int8 with per-row scale (whq byte layout: row*64 + l15*4 + ct), writes
// wscale[row], el, er. Bucket blocks: scatter (src, dst) by dst>>8 into
// contiguous runs (one global atomic per block,bucket).
__global__ __launch_bounds__(256) void k_main(const float* __restrict__ feat,
                                              const unsigned short* __restrict__ wfrag,
                                              const float* __restrict__ att_w,
                                              unsigned* __restrict__ whq32,
                                              float* __restrict__ wscale,
                                              float* __restrict__ el,
                                              float* __restrict__ er,
                                              const int* __restrict__ src,
                                              const int* __restrict__ dst,
                                              int* __restrict__ cnt,
                                              unsigned* __restrict__ pairs) {
    __shared__ unsigned short wlds[16384];  // 32 KB (gemm); aliased by bucket
    const int tid = threadIdx.x;

    if (blockIdx.x >= GEMM_BLOCKS) {
        // ---- bucket part ----
        int* lhist = (int*)wlds;
        int* lcur  = lhist + 256;
        const int bbeg = (blockIdx.x - GEMM_BLOCKS) * EPB;

        unsigned wreg[16];
        #pragma unroll
        for (int j = 0; j < 4; ++j) {
            int e0 = bbeg + j * 1024 + tid * 4;
            if (e0 + 3 < N_EDGES) {
                int4 dv = *(const int4*)(dst + e0);
                int4 sv = *(const int4*)(src + e0);
                wreg[j*4+0] = (unsigned)sv.x | ((unsigned)(dv.x & 255) << 16) | ((unsigned)(dv.x >> 8) << 24);
                wreg[j*4+1] = (unsigned)sv.y | ((unsigned)(dv.y & 255) << 16) | ((unsigned)(dv.y >> 8) << 24);
                wreg[j*4+2] = (unsigned)sv.z | ((unsigned)(dv.z & 255) << 16) | ((unsigned)(dv.z >> 8) << 24);
                wreg[j*4+3] = (unsigned)sv.w | ((unsigned)(dv.w & 255) << 16) | ((unsigned)(dv.w >> 8) << 24);
            } else {
                #pragma unroll
                for (int k = 0; k < 4; ++k) {
                    int e = e0 + k;
                    if (e < N_EDGES) {
                        int d = dst[e];
                        wreg[j*4+k] = (unsigned)src[e] | ((unsigned)(d & 255) << 16) | ((unsigned)(d >> 8) << 24);
                    } else wreg[j*4+k] = 0xFF000000u;  // sentinel bucket 255
                }
            }
        }
        if (tid < NB) lhist[tid] = 0;
        __syncthreads();
        #pragma unroll
        for (int k = 0; k < 16; ++k) {
            unsigned b = wreg[k] >> 24;
            if (b < NB) atomicAdd(&lhist[b], 1);
        }
        __syncthreads();
        if (tid < NB) {
            int c = lhist[tid];
            lcur[tid] = c ? (tid * CAP + atomicAdd(&cnt[tid], c)) : 0;
        }
        __syncthreads();
        #pragma unroll
        for (int k = 0; k < 16; ++k) {
            unsigned wv = wreg[k];
            unsigned b = wv >> 24;
            if (b < NB) {
                int pos = atomicAdd(&lcur[b], 1);
                pairs[pos] = wv & 0x00FFFFFFu;
            }
        }
        return;
    }

    // ---- gemm part: wave = 16 rows x 64 cols ----
    const int l = tid & 63, w = tid >> 6;
    const int l15 = l & 15, lg = l >> 4;
    const int wbase = blockIdx.x * 64 + w * 16;
    int ar = wbase + l15; if (ar > N_NODES - 1) ar = N_NODES - 1;
    const float* fbase = feat + (size_t)ar * IN_F + 8 * lg;

    // issue ALL 16 feat loads (full-tile MLP)
    float4 f[16];
    #pragma unroll
    for (int kt = 0; kt < 8; ++kt) {
        f[2*kt]   = *(const float4*)(fbase + kt * 32);
        f[2*kt+1] = *(const float4*)(fbase + kt * 32 + 4);
    }
    // stage wfrag -> LDS in the same vmcnt window
    #pragma unroll
    for (int i = 0; i < 8; ++i) {
        int c = tid + 256 * i;
        *(short8*)(&wlds[c * 8]) = *(const short8*)(wfrag + c * 8);
    }
    __builtin_amdgcn_sched_barrier(0);   // pin: no load sinks below this point
    __syncthreads();

    f32x4 acc[4];
    #pragma unroll
    for (int ct = 0; ct < 4; ++ct) acc[ct] = (f32x4){0.f, 0.f, 0.f, 0.f};

    #pragma unroll
    for (int kt = 0; kt < 8; ++kt) {
        float4 fa = f[2*kt], fb = f[2*kt+1];
        short8 af;
        af[0] = f2bf(fa.x); af[1] = f2bf(fa.y); af[2] = f2bf(fa.z); af[3] = f2bf(fa.w);
        af[4] = f2bf(fb.x); af[5] = f2bf(fb.y); af[6] = f2bf(fb.z); af[7] = f2bf(fb.w);
        short8 b0 = *(const short8*)(&wlds[((0 * 8 + kt) * 64 + l) * 8]);
        short8 b1 = *(const short8*)(&wlds[((1 * 8 + kt) * 64 + l) * 8]);
        short8 b2 = *(const short8*)(&wlds[((2 * 8 + kt) * 64 + l) * 8]);
        short8 b3 = *(const short8*)(&wlds[((3 * 8 + kt) * 64 + l) * 8]);
        acc[0] = __builtin_amdgcn_mfma_f32_16x16x32_bf16(af, b0, acc[0], 0, 0, 0);
        acc[1] = __builtin_amdgcn_mfma_f32_16x16x32_bf16(af, b1, acc[1], 0, 0, 0);
        acc[2] = __builtin_amdgcn_mfma_f32_16x16x32_bf16(af, b2, acc[2], 0, 0, 0);
        acc[3] = __builtin_amdgcn_mfma_f32_16x16x32_bf16(af, b3, acc[3], 0, 0, 0);
    }

    float asrc[4], adst[4];
    #pragma unroll
    for (int ct = 0; ct < 4; ++ct) {
        asrc[ct] = att_w[ct * 16 + l15];
        adst[ct] = att_w[64 + ct * 16 + l15];
    }
    #pragma unroll
    for (int j = 0; j < 4; ++j) {
        int row = wbase + lg * 4 + j;
        float v0 = acc[0][j], v1 = acc[1][j], v2 = acc[2][j], v3 = acc[3][j];
        float vs = v0 * asrc[0] + v1 * asrc[1] + v2 * asrc[2] + v3 * asrc[3];
        float vd = v0 * adst[0] + v1 * adst[1] + v2 * adst[2] + v3 * adst[3];
        float mx = fmaxf(fmaxf(fabsf(v0), fabsf(v1)), fmaxf(fabsf(v2), fabsf(v3)));
        vs += __shfl_xor(vs, 1); vd += __shfl_xor(vd, 1); mx = fmaxf(mx, __shfl_xor(mx, 1));
        vs += __shfl_xor(vs, 2); vd += __shfl_xor(vd, 2); mx = fmaxf(mx, __shfl_xor(mx, 2));
        vs += __shfl_xor(vs, 4); vd += __shfl_xor(vd, 4); mx = fmaxf(mx, __shfl_xor(mx, 4));
        vs += __shfl_xor(vs, 8); vd += __shfl_xor(vd, 8); mx = fmaxf(mx, __shfl_xor(mx, 8));
        float inv_s = (mx > 0.f) ? 127.f / mx : 0.f;
        int q0 = __float2int_rn(v0 * inv_s);
        int q1 = __float2int_rn(v1 * inv_s);
        int q2 = __float2int_rn(v2 * inv_s);
        int q3 = __float2int_rn(v3 * inv_s);
        unsigned qp = (unsigned)(q0 & 255) | ((unsigned)(q1 & 255) << 8) |
                      ((unsigned)(q2 & 255) << 16) | ((unsigned)(q3 & 255) << 24);
        if (row < N_NODES) {
            whq32[row * 16 + l15] = qp;    // byte layout: row*64 + l15*4 + ct
            if (l15 == 0) { el[row] = vs; er[row] = vd; wscale[row] = mx * (1.f / 127.f); }
        }
    }
}

// ---------------- K2: CSR build + denom (one block per 256-node bucket) --
// csr word = src(16b) | bf16(p * wscale[src])<<16, p = exp(leaky(el+er)).
// denom[node] accumulated via LDS float atomics. Segments 8-padded.
__global__ __launch_bounds__(1024) void k_build(const int* __restrict__ cnt,
                                                const unsigned* __restrict__ pairs,
                                                const float* __restrict__ el,
                                                const float* __restrict__ er,
                                                const float* __restrict__ wscale,
                                                int* __restrict__ offs,
                                                int* __restrict__ oend,
                                                float* __restrict__ denom,
                                                unsigned* __restrict__ csr) {
    __shared__ int lcnt[256], ssc[256], lcur[256];
    __shared__ float ler[256], lden[256];
    const int b = blockIdx.x;
    const int t = threadIdx.x;
    const int ebeg = b * CAP;
    const int nE = cnt[b];

    if (t < 256) {
        lcnt[t] = 0; lden[t] = 0.f;
        int node = b * 256 + t;
        ler[t] = (node < N_NODES) ? er[node] : 0.f;
    }
    __syncthreads();
    for (int i = t; i < nE; i += 1024)
        atomicAdd(&lcnt[(pairs[ebeg + i] >> 16) & 255], 1);
    __syncthreads();
    if (t < 256) ssc[t] = (lcnt[t] + 7) & ~7;   // padded count (x8)
    __syncthreads();
    for (int d = 1; d < 256; d <<= 1) {
        int v = 0;
        if (t < 256 && t >= d) v = ssc[t - d];
        __syncthreads();
        if (t < 256) ssc[t] += v;
        __syncthreads();
    }
    if (t < 256) {
        int pc = (lcnt[t] + 7) & ~7;
        int base = ssc[t] - pc;               // 8-aligned
        lcur[t] = base;
        int node = b * 256 + t;
        if (node < N_NODES) { offs[node] = ebeg + base; oend[node] = ebeg + base + pc; }
        for (int k = lcnt[t]; k < pc; ++k) csr[ebeg + base + k] = 0;  // pad
    }
    __syncthreads();
    for (int i = t; i < nE; i += 1024) {
        unsigned v = pairs[ebeg + i];
        int n8 = (v >> 16) & 255;
        int s = v & 0xFFFFu;
        float e = el[s] + ler[n8];
        e = (e > 0.f) ? e : 0.2f * e;
        float p = __expf(e);
        int pos = atomicAdd(&lcur[n8], 1);
        csr[ebeg + pos] = (unsigned)s | ((unsigned)f2bf(p * wscale[s]) << 16);
        atomicAdd(&lden[n8], p);
    }
    __syncthreads();
    if (t < 256) {
        int node = b * 256 + t;
        if (node < N_NODES) denom[node] = lden[t];
    }
}

// ---------------- K3: per-node gather — int8 rows, no den work ----------
// Wave per node. lane = (edge-slot es = l>>3, feature-group fg = l&7).
// Per iter: csr broadcast (32B window), 8B int8 row load per lane (wave
// covers 8 rows / 512B), 8x (bfe+cvt+fma). p comes pre-multiplied by the
// row scale; denom comes from k_build.
__global__ __launch_bounds__(256) void k_aggr(const int* __restrict__ offs,
                                              const int* __restrict__ oend,
                                              const unsigned* __restrict__ csr,
                                              const float* __restrict__ denom,
                                              const unsigned char* __restrict__ whq,
                                              const float* __restrict__ wscale,
                                              const float* __restrict__ bias,
                                              float* __restrict__ out) {
    const int wid = __builtin_amdgcn_readfirstlane(threadIdx.x >> 6);
    const int node = blockIdx.x * 4 + wid;
    const int lane = threadIdx.x & 63;
    const int fg = lane & 7, es = lane >> 3;
    const int beg = offs[node], end = oend[node];

    float acc[8] = {0.f, 0.f, 0.f, 0.f, 0.f, 0.f, 0.f, 0.f};
    #pragma unroll 2
    for (int jj = beg; jj < end; jj += 8) {
        unsigned e = csr[jj + es];
        float p = __uint_as_float(e & 0xFFFF0000u);   // p * wscale[s]
        uint2 wq = *(const uint2*)(whq + (size_t)(e & 0xFFFFu) * 64 + fg * 8);
        #pragma unroll
        for (int i = 0; i < 4; ++i)
            acc[i] = fmaf(p, (float)(int)(signed char)((wq.x >> (8 * i)) & 255u), acc[i]);
        #pragma unroll
        for (int i = 0; i < 4; ++i)
            acc[4 + i] = fmaf(p, (float)(int)(signed char)((wq.y >> (8 * i)) & 255u), acc[4 + i]);
    }
    #pragma unroll
    for (int i = 0; i < 8; ++i) {
        acc[i] += __shfl_xor(acc[i], 8);
        acc[i] += __shfl_xor(acc[i], 16);
        acc[i] += __shfl_xor(acc[i], 32);
    }

    if (es == 0) {
        float inv = (end > beg) ? 1.f / denom[node] : 0.f;
        uint2 wqn = *(const uint2*)(whq + (size_t)node * 64 + fg * 8);
        float sc_n = wscale[node];
        // byte i of (wq.x|wq.y): col = ct*16 + 2*fg + hi, ct = i&3, hi = i>>2
        float h[8];
        #pragma unroll
        for (int i = 0; i < 4; ++i) {
            h[i]     = acc[i]     * inv + sc_n * (float)(int)(signed char)((wqn.x >> (8 * i)) & 255u);
            h[4 + i] = acc[4 + i] * inv + sc_n * (float)(int)(signed char)((wqn.y >> (8 * i)) & 255u);
        }
        #pragma unroll
        for (int ct = 0; ct < 4; ++ct) {
            float2 bb = *(const float2*)(bias + ct * 16 + 2 * fg);
            float x0 = h[ct] + bb.x;
            float x1 = h[ct + 4] + bb.y;
            x0 = (x0 > 0.f) ? x0 : __expf(x0) - 1.f;
            x1 = (x1 > 0.f) ? x1 : __expf(x1) - 1.f;
            *(float2*)(out + (size_t)node * OUT_F + ct * 16 + 2 * fg) = make_float2(x0, x1);
        }
    }
}

extern "C" void kernel_launch(void* const* d_in, const int* in_sizes, int n_in,
                              void* d_out, int out_size, void* d_ws, size_t ws_size,
                              hipStream_t stream) {
    const float* feat  = (const float*)d_in[0];
    const float* W     = (const float*)d_in[1];
    const float* att_w = (const float*)d_in[2];
    const float* bias  = (const float*)d_in[3];
    const int*   src   = (const int*)d_in[4];
    const int*   dst   = (const int*)d_in[5];
    float* out = (float*)d_out;

    // workspace layout (4-byte words)
    unsigned* whq32 = (unsigned*)d_ws;              // 800,000 words (3.2 MB int8 Wh)
    unsigned short* wfrag = (unsigned short*)(whq32 + 800000);  // 8,192 words
    float* el      = (float*)(whq32 + 800000 + 8192);  // 50,048
    float* er      = el + 50048;                    // 50,048
    float* wscale  = er + 50048;                    // 50,048
    float* denom   = wscale + 50048;                // 50,048
    int*   offs    = (int*)(denom + 50048);         // 50,048
    int*   oend    = offs + 50048;                  // 50,048
    int*   cnt     = oend + 50048;                  // 512
    unsigned* pairs = (unsigned*)(cnt + 512);       // NB*CAP = 2,107,392 words
    unsigned* csr   = pairs + NB * CAP;             // NB*CAP = 2,107,392 words
    // total ~21.5 MB

    k_prep<<<8, 256, 0, stream>>>(W, wfrag, cnt);
    k_main<<<GEMM_BLOCKS + BK_BLOCKS, 256, 0, stream>>>(feat, wfrag, att_w, whq32, wscale,
                                                        el, er, src, dst, cnt, pairs);
    k_build<<<NB, 1024, 0, stream>>>(cnt, pairs, el, er, wscale, offs, oend, denom, csr);
    k_aggr<<<N_NODES / 4, 256, 0, stream>>>(offs, oend, csr, denom,
                                            (const unsigned char*)whq32, wscale, bias, out);
}